// Round 6
// baseline (158.369 us; speedup 1.0000x reference)
//
#include <hip/hip_runtime.h>
#include <math.h>

#define INPUT_DIM 256
#define N_CLASSES 100
#define MAX_DEPTH 12
#define N_NODES   4095
#define N_LEAVES  4096

#define TPB   512              // 8 waves, 1 block/CU (LDS ~150 KB)
#define NWAVE (TPB / 64)
#define CHUNK 64               // rows staged per chunk
#define RPW   (CHUNK / NWAVE)  // rows DMA'd per wave = 8
#define LPW   (CHUNK / NWAVE)  // traversal lanes active per wave = 8
#define ROWP  260              // padded row stride in floats (1040 B = 65*16)
#define NF4   (N_CLASSES / 4)  // 25 float4 per output row
#define NBLK  256              // 1 persistent block per CU

// Wait such that the current chunk's 8 DMAs are retired WITHOUT requiring the
// previous iteration's output stores (issued after them: <=3 per wave, 4 on
// wave 0) to drain: allow (3 stores + 8 next-chunk DMAs) = 11 outstanding.
#define WAITV(N) asm volatile("s_waitcnt vmcnt(" #N ")" ::: "memory")
#define WAITLGKM() asm volatile("s_waitcnt lgkmcnt(0)" ::: "memory")

typedef float f32x4 __attribute__((ext_vector_type(4)));

__device__ __forceinline__ void async_load16(const void* gsrc, void* ldst) {
    __builtin_amdgcn_global_load_lds(
        (const __attribute__((address_space(1))) unsigned int*)gsrc,
        (__attribute__((address_space(3))) unsigned int*)ldst, 16, 0, 0);
}

// ---------------------------------------------------------------------------
// Kernel 1: row-softmax of leaf_probabilities [4096 x 100] -> tab
// ---------------------------------------------------------------------------
__global__ __launch_bounds__(64) void softmax_rows_kernel(
    const float* __restrict__ lp, float* __restrict__ tab) {
    const int row  = blockIdx.x;
    const int lane = threadIdx.x;
    const float* src = lp + (size_t)row * N_CLASSES;

    float v0 = src[lane];
    float v1 = (lane + 64 < N_CLASSES) ? src[lane + 64] : -INFINITY;

    float m = fmaxf(v0, v1);
    #pragma unroll
    for (int off = 32; off > 0; off >>= 1) m = fmaxf(m, __shfl_xor(m, off));

    float e0 = expf(v0 - m);
    float e1 = (lane + 64 < N_CLASSES) ? expf(v1 - m) : 0.0f;
    float s = e0 + e1;
    #pragma unroll
    for (int off = 32; off > 0; off >>= 1) s += __shfl_xor(s, off);

    const float inv = 1.0f / s;
    tab[(size_t)row * N_CLASSES + lane] = e0 * inv;
    if (lane + 64 < N_CLASSES)
        tab[(size_t)row * N_CLASSES + lane + 64] = e1 * inv;
}

// ---------------------------------------------------------------------------
// Kernel 2: streamed traversal, 1 block/CU, 8 waves, CHUNK=64 double-buffered.
// DMA (global_load_lds_dwordx4, 1/row) prefetches chunk i+1 while chunk i is
// traversed. WAITV(11): only the current chunk's DMAs must retire — neither
// the prev stores nor the next chunk's DMAs are drained. Plain (cached)
// stores so store retirement happens at L2, not HBM.
// LDS: 2*64*1040 + 16380 + 4096 + 256 = 150.2 KB.
// ---------------------------------------------------------------------------
__global__ __launch_bounds__(TPB) void tree_stream_kernel(
    const float* __restrict__ x,
    const float* __restrict__ split_features,
    const float* __restrict__ split_thresholds,
    const f32x4* __restrict__ tab4,
    f32x4* __restrict__ out4,
    int batch, int nchunks) {
    __shared__ float         s_rows[2][CHUNK][ROWP];
    __shared__ float         s_thr[N_NODES];
    __shared__ unsigned char s_feat[N_NODES + 1];
    __shared__ int           s_leaf[CHUNK];

    if (blockIdx.x >= (unsigned)nchunks) return;   // block-uniform exit

    const int tid  = threadIdx.x;
    const int wid  = tid >> 6;
    const int lane = tid & 63;

    // ---- node table -> LDS ----
    for (int i = tid; i < N_NODES; i += TPB) {
        s_thr[i] = split_thresholds[i];
        int f = (int)floorf(split_features[i]);
        s_feat[i] = (unsigned char)min(max(f, 0), INPUT_DIM - 1);
    }

    // ---- stage: wave `wid` DMAs rows wid*8 .. wid*8+7 of chunk c ----
    auto stage = [&](int c, int buf) {
        const int cbase = c * CHUNK;
        #pragma unroll
        for (int j = 0; j < RPW; ++j) {
            const int r = wid * RPW + j;            // wave-uniform LDS dest base
            int s = cbase + r;
            if (s >= batch) s = batch - 1;          // clamp: loads valid data
            const float* src = x + (size_t)s * INPUT_DIM + lane * 4;
            async_load16((const void*)src, (void*)&s_rows[buf][r][0]);
        }
    };

    const int stride = gridDim.x;
    int c = blockIdx.x;

    stage(c, 0);
    __syncthreads();          // drains node-table writes AND chunk0 DMA

    int i = 0;
    for (; c < nchunks; c += stride, ++i) {
        const int cur = i & 1;

        // issue next chunk's DMA, then wait only for the CURRENT chunk's
        // DMAs (oldest ops). 11 = 3 prev-stores + 8 new DMAs may remain.
        const int cnext = c + stride;
        if (cnext < nchunks) {
            stage(cnext, cur ^ 1);
            WAITV(11);
        } else {
            WAITV(0);
        }
        __builtin_amdgcn_sched_barrier(0);
        __builtin_amdgcn_s_barrier();
        __builtin_amdgcn_sched_barrier(0);

        // ---- traversal: 8 lanes per wave, sample = wid*8 + lane ----
        if (lane < LPW) {
            const int r = wid * LPW + lane;
            const float* row = &s_rows[cur][r][0];
            int n = 0;
            #pragma unroll
            for (int d = 0; d < MAX_DEPTH; ++d) {
                const int   f = s_feat[n];
                const float t = s_thr[n];
                n = 2 * n + 1 + (row[f] > t ? 1 : 0);
            }
            s_leaf[r] = n - N_NODES;
        }
        WAITLGKM();           // commit s_leaf writes before barrier
        __builtin_amdgcn_sched_barrier(0);
        __builtin_amdgcn_s_barrier();
        __builtin_amdgcn_sched_barrier(0);

        // ---- coalesced output: out[b,:] = tab[leaf[b],:] (cached stores) ----
        const int cbase = c * CHUNK;
        const int nsamp = min(CHUNK, batch - cbase);
        const int maxj  = nsamp * NF4;
        const size_t g4 = (size_t)cbase * NF4;
        for (int j = tid; j < maxj; j += TPB) {
            const int s = j / NF4;                  // magic-div by 25
            const int q = j - s * NF4;
            out4[g4 + j] = tab4[(size_t)s_leaf[s] * NF4 + q];
        }
        // next iteration's top barrier orders s_leaf / row-buffer reuse
    }
}

// ---------------------------------------------------------------------------
// Fallback (ws too small): fully fused, per-thread softmax.
// ---------------------------------------------------------------------------
__global__ __launch_bounds__(256) void fused_kernel(
    const float* __restrict__ x,
    const float* __restrict__ split_features,
    const float* __restrict__ split_thresholds,
    const float* __restrict__ lp,
    float* __restrict__ out, int batch) {
    __shared__ float2 s_nodes[N_NODES];
    for (int i = threadIdx.x; i < N_NODES; i += blockDim.x) {
        int f = (int)floorf(split_features[i]);
        f = min(max(f, 0), INPUT_DIM - 1);
        float2 n; n.x = split_thresholds[i]; n.y = __int_as_float(f);
        s_nodes[i] = n;
    }
    __syncthreads();

    const int b = blockIdx.x * blockDim.x + threadIdx.x;
    if (b >= batch) return;

    const float* row = x + (size_t)b * INPUT_DIM;
    int node = 0;
    #pragma unroll
    for (int d = 0; d < MAX_DEPTH; ++d) {
        const float2 n = s_nodes[node];
        const float val = row[__float_as_int(n.y)];
        node = 2 * node + 1 + (val > n.x ? 1 : 0);
    }
    const int leaf = node - N_NODES;

    const float* src = lp + (size_t)leaf * N_CLASSES;
    float m = -INFINITY;
    for (int cidx = 0; cidx < N_CLASSES; ++cidx) m = fmaxf(m, src[cidx]);
    float s = 0.0f;
    float e[N_CLASSES];
    for (int cidx = 0; cidx < N_CLASSES; ++cidx) { e[cidx] = expf(src[cidx] - m); s += e[cidx]; }
    const float inv = 1.0f / s;
    float* dst = out + (size_t)b * N_CLASSES;
    for (int cidx = 0; cidx < N_CLASSES; ++cidx) dst[cidx] = e[cidx] * inv;
}

// ---------------------------------------------------------------------------
extern "C" void kernel_launch(void* const* d_in, const int* in_sizes, int n_in,
                              void* d_out, int out_size, void* d_ws, size_t ws_size,
                              hipStream_t stream) {
    const float* x  = (const float*)d_in[0];
    const float* sf = (const float*)d_in[1];
    const float* st = (const float*)d_in[2];
    const float* lp = (const float*)d_in[3];
    float* out = (float*)d_out;

    const int batch = in_sizes[0] / INPUT_DIM;

    const size_t tab_bytes = (size_t)N_LEAVES * N_CLASSES * sizeof(float); // 1.6384 MB

    if (ws_size >= tab_bytes && batch > 0) {
        float* tab = (float*)d_ws;

        softmax_rows_kernel<<<N_LEAVES, 64, 0, stream>>>(lp, tab);

        const int nchunks = (batch + CHUNK - 1) / CHUNK;
        const int nblk = nchunks < NBLK ? nchunks : NBLK;
        tree_stream_kernel<<<nblk, TPB, 0, stream>>>(
            x, sf, st, (const f32x4*)tab, (f32x4*)out, batch, nchunks);
    } else {
        fused_kernel<<<(batch + 255) / 256, 256, 0, stream>>>(
            x, sf, st, lp, out, batch);
    }
}

// Round 7
// 153.921 us; speedup vs baseline: 1.0289x; 1.0289x over previous
//
#include <hip/hip_runtime.h>
#include <math.h>

#define INPUT_DIM 256
#define N_CLASSES 100
#define MAX_DEPTH 12
#define N_NODES   4095
#define N_LEAVES  4096

#define TPB   512              // 8 waves, 1 block/CU (LDS ~142 KB)
#define NWAVE 8
#define RPW   5                // rows per unit per wave-pipeline (500000 % 5 == 0)
#define DEPTH 3                // triple buffer: prefetch distance 2
#define ROWP  260              // padded row stride in floats (1040 B = 65*16)
#define NF4   (N_CLASSES / 4)  // 25 float4 per output row
#define NBLK  256              // 1 block per CU -> 2048 independent wave-pipelines

#define WAITV(N) asm volatile("s_waitcnt vmcnt(" #N ")" ::: "memory")
#define SCHEDB() __builtin_amdgcn_sched_barrier(0)

typedef float f32x4 __attribute__((ext_vector_type(4)));

__device__ __forceinline__ void async_load16(const void* gsrc, void* ldst) {
    __builtin_amdgcn_global_load_lds(
        (const __attribute__((address_space(1))) unsigned int*)gsrc,
        (__attribute__((address_space(3))) unsigned int*)ldst, 16, 0, 0);
}

// ---------------------------------------------------------------------------
// Kernel 1: row-softmax of leaf_probabilities [4096 x 100] -> tab
// ---------------------------------------------------------------------------
__global__ __launch_bounds__(64) void softmax_rows_kernel(
    const float* __restrict__ lp, float* __restrict__ tab) {
    const int row  = blockIdx.x;
    const int lane = threadIdx.x;
    const float* src = lp + (size_t)row * N_CLASSES;

    float v0 = src[lane];
    float v1 = (lane + 64 < N_CLASSES) ? src[lane + 64] : -INFINITY;

    float m = fmaxf(v0, v1);
    #pragma unroll
    for (int off = 32; off > 0; off >>= 1) m = fmaxf(m, __shfl_xor(m, off));

    float e0 = expf(v0 - m);
    float e1 = (lane + 64 < N_CLASSES) ? expf(v1 - m) : 0.0f;
    float s = e0 + e1;
    #pragma unroll
    for (int off = 32; off > 0; off >>= 1) s += __shfl_xor(s, off);

    const float inv = 1.0f / s;
    tab[(size_t)row * N_CLASSES + lane] = e0 * inv;
    if (lane + 64 < N_CLASSES)
        tab[(size_t)row * N_CLASSES + lane + 64] = e1 * inv;
}

// ---------------------------------------------------------------------------
// Kernel 2: barrier-free streamed traversal. Each wave is an independent
// pipeline over its own 5-row LDS slice: DMA (global_load_lds_dwordx4,
// 1 KB/row), triple-buffered with prefetch distance 2; per-wave counted
// vmcnt only (steady WAITV(18) = 4 out-ops + 5 DMA + 4 + 5 newer than the
// awaited unit). Traversal: 5 chains/wave, both children's (thr,feat)
// speculatively loaded so the chain is one LDS row-gather per level.
// Output: leaf via __shfl, tab row gathered from L2, nontemporal stores.
// LDS: 8*3*5*1040 + 16380 + 4096 = 145276 B (~142 KB) -> 1 block/CU.
// ---------------------------------------------------------------------------
__global__ __launch_bounds__(TPB) void tree_stream_kernel(
    const float* __restrict__ x,
    const float* __restrict__ split_features,
    const float* __restrict__ split_thresholds,
    const f32x4* __restrict__ tab4,
    f32x4* __restrict__ out4,
    int batch, int nunits) {
    __shared__ float         s_rows[NWAVE][DEPTH][RPW][ROWP];
    __shared__ float         s_thr[N_NODES];
    __shared__ unsigned char s_feat[N_NODES + 1];

    const int tid  = threadIdx.x;
    const int wid  = tid >> 6;
    const int lane = tid & 63;

    // ---- node table -> LDS (once) ----
    for (int i = tid; i < N_NODES; i += TPB) {
        s_thr[i] = split_thresholds[i];
        int f = (int)floorf(split_features[i]);
        s_feat[i] = (unsigned char)min(max(f, 0), INPUT_DIM - 1);
    }
    __syncthreads();          // only barrier in the kernel

    const int NPIPE = gridDim.x * NWAVE;            // total pipelines
    const int W     = blockIdx.x * NWAVE + wid;     // this pipeline's id

    // stage unit k (clamped) into buffer slot: 5 DMAs, wave-uniform LDS dest
    auto stage = [&](int k, int slot) {
        long g = (long)W + (long)k * NPIPE;
        if (g >= nunits) g = nunits - 1;            // dummy (valid) traffic
        const size_t rbase = (size_t)g * RPW;
        #pragma unroll
        for (int j = 0; j < RPW; ++j) {
            const float* src = x + (rbase + j) * INPUT_DIM + lane * 4;
            async_load16((const void*)src, (void*)&s_rows[wid][slot][j][0]);
        }
    };

    stage(0, 0);
    stage(1, 1);

    for (int k = 0; ; ++k) {
        const long g = (long)W + (long)k * NPIPE;
        if (g >= nunits) break;                     // wave-uniform exit

        stage(k + 2, (k + 2) % 3);                  // prefetch distance 2
        SCHEDB();
        if (k == 0)      WAITV(10);                 // newer: stage1(5)+stage2(5)
        else if (k == 1) WAITV(14);                 // stage2(5)+out0(4)+stage3(5)
        else             WAITV(18);                 // out(4)+stage(5)+out(4)+stage(5)
        SCHEDB();

        // ---- traversal: lanes 0..4, one chain each; children speculated ----
        int leaf = 0;
        if (lane < RPW) {
            const float* row = &s_rows[wid][k % 3][lane][0];
            float t = s_thr[0];
            int   f = s_feat[0];
            int   n = 0;
            #pragma unroll
            for (int d = 0; d < MAX_DEPTH; ++d) {
                const int l = 2 * n + 1;
                if (d < MAX_DEPTH - 1) {
                    const float tl = s_thr[l],  tr = s_thr[l + 1];
                    const int   fl = s_feat[l], fr = s_feat[l + 1];
                    const int go = row[f] > t ? 1 : 0;   // chain: row gather only
                    t = go ? tr : tl;
                    f = go ? fr : fl;
                    n = l + go;
                } else {
                    n = l + (row[f] > t ? 1 : 0);
                }
            }
            leaf = n - N_NODES;
        }

        // ---- output: 5 rows x 25 f32x4 = 125; lanes j and j+64 ----
        const size_t base4 = (size_t)g * (RPW * NF4);
        const long   rem   = (long)batch * NF4 - (long)base4;
        const int    maxj  = rem < RPW * NF4 ? (int)rem : RPW * NF4;
        #pragma unroll
        for (int t2 = 0; t2 < 2; ++t2) {
            const int j = lane + t2 * 64;
            if (j < maxj) {
                const int r = j / NF4;              // 0..4
                const int q = j - r * NF4;
                const int lf = __shfl(leaf, r);
                f32x4 v = tab4[(size_t)lf * NF4 + q];
                __builtin_nontemporal_store(v, &out4[base4 + j]);
            }
        }
    }
}

// ---------------------------------------------------------------------------
// Fallback (ws too small): fully fused, per-thread softmax.
// ---------------------------------------------------------------------------
__global__ __launch_bounds__(256) void fused_kernel(
    const float* __restrict__ x,
    const float* __restrict__ split_features,
    const float* __restrict__ split_thresholds,
    const float* __restrict__ lp,
    float* __restrict__ out, int batch) {
    __shared__ float2 s_nodes[N_NODES];
    for (int i = threadIdx.x; i < N_NODES; i += blockDim.x) {
        int f = (int)floorf(split_features[i]);
        f = min(max(f, 0), INPUT_DIM - 1);
        float2 n; n.x = split_thresholds[i]; n.y = __int_as_float(f);
        s_nodes[i] = n;
    }
    __syncthreads();

    const int b = blockIdx.x * blockDim.x + threadIdx.x;
    if (b >= batch) return;

    const float* row = x + (size_t)b * INPUT_DIM;
    int node = 0;
    #pragma unroll
    for (int d = 0; d < MAX_DEPTH; ++d) {
        const float2 n = s_nodes[node];
        const float val = row[__float_as_int(n.y)];
        node = 2 * node + 1 + (val > n.x ? 1 : 0);
    }
    const int leaf = node - N_NODES;

    const float* src = lp + (size_t)leaf * N_CLASSES;
    float m = -INFINITY;
    for (int cidx = 0; cidx < N_CLASSES; ++cidx) m = fmaxf(m, src[cidx]);
    float s = 0.0f;
    float e[N_CLASSES];
    for (int cidx = 0; cidx < N_CLASSES; ++cidx) { e[cidx] = expf(src[cidx] - m); s += e[cidx]; }
    const float inv = 1.0f / s;
    float* dst = out + (size_t)b * N_CLASSES;
    for (int cidx = 0; cidx < N_CLASSES; ++cidx) dst[cidx] = e[cidx] * inv;
}

// ---------------------------------------------------------------------------
extern "C" void kernel_launch(void* const* d_in, const int* in_sizes, int n_in,
                              void* d_out, int out_size, void* d_ws, size_t ws_size,
                              hipStream_t stream) {
    const float* x  = (const float*)d_in[0];
    const float* sf = (const float*)d_in[1];
    const float* st = (const float*)d_in[2];
    const float* lp = (const float*)d_in[3];
    float* out = (float*)d_out;

    const int batch = in_sizes[0] / INPUT_DIM;

    const size_t tab_bytes = (size_t)N_LEAVES * N_CLASSES * sizeof(float); // 1.6384 MB

    if (ws_size >= tab_bytes && batch > 0) {
        float* tab = (float*)d_ws;

        softmax_rows_kernel<<<N_LEAVES, 64, 0, stream>>>(lp, tab);

        const int nunits = (batch + RPW - 1) / RPW;
        int nblk = (nunits + NWAVE - 1) / NWAVE;
        if (nblk > NBLK) nblk = NBLK;
        tree_stream_kernel<<<nblk, TPB, 0, stream>>>(
            x, sf, st, (const f32x4*)tab, (f32x4*)out, batch, nunits);
    } else {
        fused_kernel<<<(batch + 255) / 256, 256, 0, stream>>>(
            x, sf, st, lp, out, batch);
    }
}

// Round 8
// 140.249 us; speedup vs baseline: 1.1292x; 1.0975x over previous
//
#include <hip/hip_runtime.h>
#include <math.h>

#define INPUT_DIM 256
#define N_CLASSES 100
#define MAX_DEPTH 12
#define N_NODES   4095
#define N_LEAVES  4096

#define TPB   512              // 8 waves, 1 block/CU (LDS ~142 KB)
#define NWAVE 8
#define RPW   5                // rows per unit per wave-pipeline
#define DEPTH 3                // triple buffer: prefetch distance 2
#define ROWP  260              // padded row stride in floats (1040 B = 65*16)
#define NF4   (N_CLASSES / 4)  // 25 float4 per output row
#define NBLK  256              // 1 block per CU -> 2048 independent wave-pipelines

#define WAITV(N) asm volatile("s_waitcnt vmcnt(" #N ")" ::: "memory")
#define SCHEDB() __builtin_amdgcn_sched_barrier(0)

typedef float f32x4 __attribute__((ext_vector_type(4)));

__device__ __forceinline__ void async_load16(const void* gsrc, void* ldst) {
    __builtin_amdgcn_global_load_lds(
        (const __attribute__((address_space(1))) unsigned int*)gsrc,
        (__attribute__((address_space(3))) unsigned int*)ldst, 16, 0, 0);
}

// ---------------------------------------------------------------------------
// Kernel 1: row-softmax of leaf_probabilities [4096 x 100] -> tab
// ---------------------------------------------------------------------------
__global__ __launch_bounds__(64) void softmax_rows_kernel(
    const float* __restrict__ lp, float* __restrict__ tab) {
    const int row  = blockIdx.x;
    const int lane = threadIdx.x;
    const float* src = lp + (size_t)row * N_CLASSES;

    float v0 = src[lane];
    float v1 = (lane + 64 < N_CLASSES) ? src[lane + 64] : -INFINITY;

    float m = fmaxf(v0, v1);
    #pragma unroll
    for (int off = 32; off > 0; off >>= 1) m = fmaxf(m, __shfl_xor(m, off));

    float e0 = expf(v0 - m);
    float e1 = (lane + 64 < N_CLASSES) ? expf(v1 - m) : 0.0f;
    float s = e0 + e1;
    #pragma unroll
    for (int off = 32; off > 0; off >>= 1) s += __shfl_xor(s, off);

    const float inv = 1.0f / s;
    tab[(size_t)row * N_CLASSES + lane] = e0 * inv;
    if (lane + 64 < N_CLASSES)
        tab[(size_t)row * N_CLASSES + lane + 64] = e1 * inv;
}

// ---------------------------------------------------------------------------
// Kernel 2: PURE-READ streamed traversal (no output phase). Barrier-free
// wave-pipelines: each wave triple-buffers its own 5-row LDS slice via
// global_load_lds_dwordx4 (1 KB/row), prefetch distance 2, per-wave counted
// vmcnt. Traversal: 5 chains/wave, children (thr,feat) speculated so the
// dependent chain is one LDS row-gather per level. Only output: u16 leaf id
// per sample (1 MB total).
// vmcnt ops/unit: 5 DMA + 1 leaf-store = 6; steady wait = 5+1+5+1 = 12.
// LDS: 8*3*5*1040 + 16380 + 4096 = ~142 KB -> 1 block/CU.
// ---------------------------------------------------------------------------
__global__ __launch_bounds__(TPB) void traverse_kernel(
    const float* __restrict__ x,
    const float* __restrict__ split_features,
    const float* __restrict__ split_thresholds,
    unsigned short* __restrict__ leaf_out,
    int batch, int nunits) {
    __shared__ float         s_rows[NWAVE][DEPTH][RPW][ROWP];
    __shared__ float         s_thr[N_NODES];
    __shared__ unsigned char s_feat[N_NODES + 1];

    const int tid  = threadIdx.x;
    const int wid  = tid >> 6;
    const int lane = tid & 63;

    // ---- node table -> LDS (once) ----
    for (int i = tid; i < N_NODES; i += TPB) {
        s_thr[i] = split_thresholds[i];
        int f = (int)floorf(split_features[i]);
        s_feat[i] = (unsigned char)min(max(f, 0), INPUT_DIM - 1);
    }
    __syncthreads();          // only barrier in the kernel

    const int NPIPE = gridDim.x * NWAVE;
    const int W     = blockIdx.x * NWAVE + wid;

    // stage unit k (clamped -> dummy loads hit the same hot lines) into slot
    auto stage = [&](int k, int slot) {
        long g = (long)W + (long)k * NPIPE;
        if (g >= nunits) g = nunits - 1;
        #pragma unroll
        for (int j = 0; j < RPW; ++j) {
            long r = g * RPW + j;
            if (r >= batch) r = batch - 1;
            const float* src = x + (size_t)r * INPUT_DIM + lane * 4;
            async_load16((const void*)src, (void*)&s_rows[wid][slot][j][0]);
        }
    };

    stage(0, 0);
    stage(1, 1);

    for (int k = 0; ; ++k) {
        const long g = (long)W + (long)k * NPIPE;
        if (g >= nunits) break;                     // wave-uniform exit

        stage(k + 2, (k + 2) % 3);                  // prefetch distance 2
        SCHEDB();
        if (k == 0)      WAITV(10);                 // stage1(5)+stage2(5) newer
        else if (k == 1) WAITV(11);                 // st0(1)+stage2(5)+stage3(5)
        else             WAITV(12);                 // st+stage+st+stage newer
        SCHEDB();

        // ---- traversal: lanes 0..4, one chain each; children speculated ----
        if (lane < RPW) {
            const float* row = &s_rows[wid][k % 3][lane][0];
            float t = s_thr[0];
            int   f = s_feat[0];
            int   n = 0;
            #pragma unroll
            for (int d = 0; d < MAX_DEPTH; ++d) {
                const int l = 2 * n + 1;
                if (d < MAX_DEPTH - 1) {
                    const float tl = s_thr[l],  tr = s_thr[l + 1];
                    const int   fl = s_feat[l], fr = s_feat[l + 1];
                    const int go = row[f] > t ? 1 : 0;   // chain: row gather only
                    t = go ? tr : tl;
                    f = go ? fr : fl;
                    n = l + go;
                } else {
                    n = l + (row[f] > t ? 1 : 0);
                }
            }
            const long s = g * RPW + lane;
            if (s < batch)
                leaf_out[s] = (unsigned short)(n - N_NODES);
        }
    }
}

// ---------------------------------------------------------------------------
// Kernel 3: PURE-WRITE gather. out4[j] = tab4[leaf[j/25]*25 + j%25].
// Grid-stride thread-per-float4; leaf u16 reads are L1/L2-hot, tab reads are
// L2-resident (1.6 MB), stores are coalesced nontemporal.
// ---------------------------------------------------------------------------
__global__ __launch_bounds__(256) void gather_out_kernel(
    const f32x4* __restrict__ tab4,
    const unsigned short* __restrict__ leaf,
    f32x4* __restrict__ out4, int total4) {
    for (int j = blockIdx.x * 256 + threadIdx.x; j < total4;
         j += gridDim.x * 256) {
        const int r = j / NF4;                 // magic-div by 25
        const int q = j - r * NF4;
        const int lf = leaf[r];
        f32x4 v = tab4[(size_t)lf * NF4 + q];
        __builtin_nontemporal_store(v, &out4[j]);
    }
}

// ---------------------------------------------------------------------------
// Fallback (ws too small): fully fused, per-thread softmax.
// ---------------------------------------------------------------------------
__global__ __launch_bounds__(256) void fused_kernel(
    const float* __restrict__ x,
    const float* __restrict__ split_features,
    const float* __restrict__ split_thresholds,
    const float* __restrict__ lp,
    float* __restrict__ out, int batch) {
    __shared__ float2 s_nodes[N_NODES];
    for (int i = threadIdx.x; i < N_NODES; i += blockDim.x) {
        int f = (int)floorf(split_features[i]);
        f = min(max(f, 0), INPUT_DIM - 1);
        float2 n; n.x = split_thresholds[i]; n.y = __int_as_float(f);
        s_nodes[i] = n;
    }
    __syncthreads();

    const int b = blockIdx.x * blockDim.x + threadIdx.x;
    if (b >= batch) return;

    const float* row = x + (size_t)b * INPUT_DIM;
    int node = 0;
    #pragma unroll
    for (int d = 0; d < MAX_DEPTH; ++d) {
        const float2 n = s_nodes[node];
        const float val = row[__float_as_int(n.y)];
        node = 2 * node + 1 + (val > n.x ? 1 : 0);
    }
    const int leaf = node - N_NODES;

    const float* src = lp + (size_t)leaf * N_CLASSES;
    float m = -INFINITY;
    for (int cidx = 0; cidx < N_CLASSES; ++cidx) m = fmaxf(m, src[cidx]);
    float s = 0.0f;
    float e[N_CLASSES];
    for (int cidx = 0; cidx < N_CLASSES; ++cidx) { e[cidx] = expf(src[cidx] - m); s += e[cidx]; }
    const float inv = 1.0f / s;
    float* dst = out + (size_t)b * N_CLASSES;
    for (int cidx = 0; cidx < N_CLASSES; ++cidx) dst[cidx] = e[cidx] * inv;
}

// ---------------------------------------------------------------------------
extern "C" void kernel_launch(void* const* d_in, const int* in_sizes, int n_in,
                              void* d_out, int out_size, void* d_ws, size_t ws_size,
                              hipStream_t stream) {
    const float* x  = (const float*)d_in[0];
    const float* sf = (const float*)d_in[1];
    const float* st = (const float*)d_in[2];
    const float* lp = (const float*)d_in[3];
    float* out = (float*)d_out;

    const int batch = in_sizes[0] / INPUT_DIM;

    const size_t tab_bytes = (size_t)N_LEAVES * N_CLASSES * sizeof(float); // 1.6384 MB
    const size_t need = tab_bytes + (size_t)batch * sizeof(unsigned short);

    if (ws_size >= need && batch > 0) {
        float* tab = (float*)d_ws;
        unsigned short* leaf = (unsigned short*)((char*)d_ws + tab_bytes);

        softmax_rows_kernel<<<N_LEAVES, 64, 0, stream>>>(lp, tab);

        const int nunits = (batch + RPW - 1) / RPW;
        int nblk = (nunits + NWAVE - 1) / NWAVE;
        if (nblk > NBLK) nblk = NBLK;
        traverse_kernel<<<nblk, TPB, 0, stream>>>(
            x, sf, st, leaf, batch, nunits);

        const int total4 = batch * NF4;
        int nb2 = (total4 + 255) / 256;
        if (nb2 > 2048) nb2 = 2048;
        gather_out_kernel<<<nb2, 256, 0, stream>>>(
            (const f32x4*)tab, leaf, (f32x4*)out, total4);
    } else {
        fused_kernel<<<(batch + 255) / 256, 256, 0, stream>>>(
            x, sf, st, lp, out, batch);
    }
}